// Round 16
// baseline (158.786 us; speedup 1.0000x reference)
//
#include <hip/hip_runtime.h>

typedef short short8 __attribute__((ext_vector_type(8)));
typedef float f32x4 __attribute__((ext_vector_type(4)));
typedef unsigned int uint4v __attribute__((ext_vector_type(4)));

#define H_ 384
#define W_ 384
#define C_ 32
#define HW_ 147456          // H_*W_
#define HP1F 385.0f         // (H+2*pad)-1 as float
#define NB 2                // pixel batches per wave (interleaved in R16)
#define PW 386              // padded width/height
#define PROW (PW * C_)      // 12352 elems per padded row
#define XPAD_ELEMS (2 * PW * PW * C_)   // 9,533,504 bf16
#define XPAD_BYTES ((size_t)XPAD_ELEMS * 2)

__device__ __forceinline__ unsigned short f2bf(float f) {
  unsigned int u = __float_as_uint(f);
  u += 0x7fffu + ((u >> 16) & 1u);   // RNE
  return (unsigned short)(u >> 16);
}

__device__ __forceinline__ unsigned pack2(float a, float b) {
  return (unsigned)f2bf(a) | ((unsigned)f2bf(b) << 16);
}

// 8 bf16 (uint4) -> 8 f32, pure bit ops (exact). Memory order ch0..ch7.
__device__ __forceinline__ void b8_to_f(uint4 r, f32x4& lo, f32x4& hi) {
  lo[0] = __uint_as_float(r.x << 16);
  lo[1] = __uint_as_float(r.x & 0xffff0000u);
  lo[2] = __uint_as_float(r.y << 16);
  lo[3] = __uint_as_float(r.y & 0xffff0000u);
  hi[0] = __uint_as_float(r.z << 16);
  hi[1] = __uint_as_float(r.z & 0xffff0000u);
  hi[2] = __uint_as_float(r.w << 16);
  hi[3] = __uint_as_float(r.w & 0xffff0000u);
}

// ---------------------------------------------------------------------------
// R16: R10/R15 math with the two NB pixel-streams INTERLEAVED in one fused
// tap loop. All prior levers attacked single-stream ILP (R5: neutral),
// VALU count (R11: hurt), or occupancy (R12: spilled). This is the untested
// MLP dimension: 8 independent gathers in flight per tap (2 streams x 4
// corners) instead of 4, at ~110 VGPR — inside the same 4-waves/SIMD band
// (cliff at 128). Single tap state per stream; compiler schedules waits.
// Per-pixel arithmetic identical to R15 -> absmax must stay 0.015625.
// ---------------------------------------------------------------------------

__global__ __launch_bounds__(256) void deform_conv_d(
    const unsigned short* __restrict__ xb, const float* __restrict__ off,
    const float* __restrict__ kern, const float* __restrict__ bias,
    float* __restrict__ out) {
  __shared__ short ldsB[9216];

  const int tid = threadIdx.x;
  const int lane = tid & 63;

  // ---- stage packed B fragments (bf16, MFMA B-operand layout) into LDS ----
  {
    unsigned short* pk = (unsigned short*)ldsB;
    for (int e = tid; e < 1152; e += 256) {   // 2 f-tiles * 9 k-steps * 64 lanes
      const int ln = e & 63;
      const int kk = (e >> 6) % 9;
      const int nt = e / 576;
      const int f = nt * 16 + (ln & 15);
      const int q2 = ln >> 4;
      unsigned short rr[8];
#pragma unroll
      for (int i2 = 0; i2 < 8; ++i2) {
        const int c = q2 * 8 + i2;                     // contraction idx = kk*32 + c
        rr[i2] = f2bf(kern[(kk * 32 + c) * 32 + f]);
      }
      uint4 w;
      w.x = rr[0] | ((unsigned)rr[1] << 16);
      w.y = rr[2] | ((unsigned)rr[3] << 16);
      w.z = rr[4] | ((unsigned)rr[5] << 16);
      w.w = rr[6] | ((unsigned)rr[7] << 16);
      *(uint4*)&pk[e * 8] = w;
    }
    __syncthreads();   // only barrier in the kernel
  }
  const short8* bp = (const short8*)ldsB;

  const float bias0 = bias[lane & 15];
  const float bias1 = bias[16 + (lane & 15)];

  // direct MFMA lane mapping: pixel = mrow, K-slice = qq*8..+7
  const int mrow = lane & 15;
  const int qq = lane >> 4;
  const int c0 = qq * 8;

  const int lb = (blockIdx.x & 7) * 288 + (blockIdx.x >> 3);
  const int wv = tid >> 6;

  // ---- stream setup: nb=0 -> stream A, nb=1 -> stream B ----
  const int gA = lb * (4 * NB) + 0 * 4 + wv;
  const int gB = lb * (4 * NB) + 1 * 4 + wv;
  const int P0A = gA << 4;
  const int P0B = gB << 4;
  const int bA = (P0A >= HW_) ? 1 : 0;
  const int bB = (P0B >= HW_) ? 1 : 0;
  const int remA = P0A - bA * HW_;
  const int remB = P0B - bB * HW_;
  const int iA = remA / W_;
  const int iB = remB / W_;
  const int jA = (remA - iA * W_) + mrow;
  const int jB = (remB - iB * W_) + mrow;

  const float* opixA = off + (size_t)(iA * W_ + jA) * 18;
  const float* opixB = off + (size_t)(iB * W_ + jB) * 18;

  f32x4 accA0 = {bias0, bias0, bias0, bias0};
  f32x4 accA1 = {bias1, bias1, bias1, bias1};
  f32x4 accB0 = {bias0, bias0, bias0, bias0};
  f32x4 accB1 = {bias1, bias1, bias1, bias1};

  // ---- fused tap loop: both streams per iteration (8 gathers in flight) ----
#pragma unroll
  for (int kk = 0; kk < 9; ++kk) {
    const int di = kk / 3;
    const int dj = kk - di * 3;
    const float2 oA = *(const float2*)(opixA + kk * 2);
    const float2 oB = *(const float2*)(opixB + kk * 2);

    // stream A coords/weights/addresses
    float yfA = (float)(iA + di) + oA.y;
    float xfA = (float)(jA + dj) + oA.x;
    yfA = fminf(fmaxf(yfA, 0.f), HP1F);
    xfA = fminf(fmaxf(xfA, 0.f), HP1F);
    const float y0fA = floorf(yfA), x0fA = floorf(xfA);
    const int y0A = (int)y0fA, x0A = (int)x0fA;
    const int y1A = min(y0A + 1, 385), x1A = min(x0A + 1, 385);
    const float wy1A = yfA - y0fA, wy0A = (float)y1A - yfA;
    const float wx1A = xfA - x0fA, wx0A = (float)x1A - xfA;
    const float wA00 = wy0A * wx0A, wA01 = wy0A * wx1A;
    const float wA10 = wy1A * wx0A, wA11 = wy1A * wx1A;
    const int baseA = ((bA * PW + y0A) * PW + x0A) * C_ + c0;
    const int dxA = (x1A - x0A) * C_;
    const int dyA = (y1A - y0A) * PROW;

    // stream B coords/weights/addresses
    float yfB = (float)(iB + di) + oB.y;
    float xfB = (float)(jB + dj) + oB.x;
    yfB = fminf(fmaxf(yfB, 0.f), HP1F);
    xfB = fminf(fmaxf(xfB, 0.f), HP1F);
    const float y0fB = floorf(yfB), x0fB = floorf(xfB);
    const int y0B = (int)y0fB, x0B = (int)x0fB;
    const int y1B = min(y0B + 1, 385), x1B = min(x0B + 1, 385);
    const float wy1B = yfB - y0fB, wy0B = (float)y1B - yfB;
    const float wx1B = xfB - x0fB, wx0B = (float)x1B - xfB;
    const float wB00 = wy0B * wx0B, wB01 = wy0B * wx1B;
    const float wB10 = wy1B * wx0B, wB11 = wy1B * wx1B;
    const int baseB = ((bB * PW + y0B) * PW + x0B) * C_ + c0;
    const int dxB = (x1B - x0B) * C_;
    const int dyB = (y1B - y0B) * PROW;

    // 8 unconditional independent 16B gathers (both streams in flight)
    const uint4 rA00 = *(const uint4*)(xb + baseA);
    const uint4 rA01 = *(const uint4*)(xb + baseA + dxA);
    const uint4 rA10 = *(const uint4*)(xb + baseA + dyA);
    const uint4 rA11 = *(const uint4*)(xb + baseA + dyA + dxA);
    const uint4 rB00 = *(const uint4*)(xb + baseB);
    const uint4 rB01 = *(const uint4*)(xb + baseB + dxB);
    const uint4 rB10 = *(const uint4*)(xb + baseB + dyB);
    const uint4 rB11 = *(const uint4*)(xb + baseB + dyB + dxB);

    // stream A: unpack + interp + pack + MFMA
    {
      f32x4 l00, h00, l01, h01, l10, h10, l11, h11;
      b8_to_f(rA00, l00, h00);
      b8_to_f(rA01, l01, h01);
      b8_to_f(rA10, l10, h10);
      b8_to_f(rA11, l11, h11);
      const f32x4 vlo = wA00 * l00 + wA01 * l01 + wA10 * l10 + wA11 * l11;
      const f32x4 vhi = wA00 * h00 + wA01 * h01 + wA10 * h10 + wA11 * h11;
      const uint4v uu = {pack2(vlo[0], vlo[1]), pack2(vlo[2], vlo[3]),
                         pack2(vhi[0], vhi[1]), pack2(vhi[2], vhi[3])};
      const short8 af = __builtin_bit_cast(short8, uu);
      accA0 = __builtin_amdgcn_mfma_f32_16x16x32_bf16(af, bp[kk * 64 + lane], accA0, 0, 0, 0);
      accA1 = __builtin_amdgcn_mfma_f32_16x16x32_bf16(af, bp[(9 + kk) * 64 + lane], accA1, 0, 0, 0);
    }
    // stream B: unpack + interp + pack + MFMA
    {
      f32x4 l00, h00, l01, h01, l10, h10, l11, h11;
      b8_to_f(rB00, l00, h00);
      b8_to_f(rB01, l01, h01);
      b8_to_f(rB10, l10, h10);
      b8_to_f(rB11, l11, h11);
      const f32x4 vlo = wB00 * l00 + wB01 * l01 + wB10 * l10 + wB11 * l11;
      const f32x4 vhi = wB00 * h00 + wB01 * h01 + wB10 * h10 + wB11 * h11;
      const uint4v uu = {pack2(vlo[0], vlo[1]), pack2(vlo[2], vlo[3]),
                         pack2(vhi[0], vhi[1]), pack2(vhi[2], vhi[3])};
      const short8 af = __builtin_bit_cast(short8, uu);
      accB0 = __builtin_amdgcn_mfma_f32_16x16x32_bf16(af, bp[kk * 64 + lane], accB0, 0, 0, 0);
      accB1 = __builtin_amdgcn_mfma_f32_16x16x32_bf16(af, bp[(9 + kk) * 64 + lane], accB1, 0, 0, 0);
    }
  }

  // D layout: col = lane&15, row = qq*4 + reg — both streams
  {
    float* op = out + (size_t)(P0A + qq * 4) * 32 + (lane & 15);
#pragma unroll
    for (int r = 0; r < 4; ++r) {
      op[r * 32] = accA0[r];
      op[r * 32 + 16] = accA1[r];
    }
  }
  {
    float* op = out + (size_t)(P0B + qq * 4) * 32 + (lane & 15);
#pragma unroll
    for (int r = 0; r < 4; ++r) {
      op[r * 32] = accB0[r];
      op[r * 32 + 16] = accB1[r];
    }
  }
}

// pre-pass: x f32 -> PADDED bf16 workspace [2][386][386][32], zero borders.
__global__ __launch_bounds__(256) void cvt_pad_kernel(
    const float* __restrict__ x, unsigned short* __restrict__ xb) {
  const int total = 2 * PW * PW * 4;   // 8-channel groups
  for (int t = blockIdx.x * 256 + threadIdx.x; t < total; t += gridDim.x * 256) {
    const int c8 = t & 3;
    const int p  = t >> 2;             // padded pixel index
    const int xp = p % PW;
    const int yp = (p / PW) % PW;
    const int b  = p / (PW * PW);
    uint4 w = {0u, 0u, 0u, 0u};
    const unsigned py = (unsigned)(yp - 1), px = (unsigned)(xp - 1);
    if (py < 384u && px < 384u) {
      const float* src = x + (((size_t)(b * H_ + (int)py) * W_ + (int)px) * C_ + c8 * 8);
      const float4 v0 = *(const float4*)(src);
      const float4 v1 = *(const float4*)(src + 4);
      w.x = pack2(v0.x, v0.y);
      w.y = pack2(v0.z, v0.w);
      w.z = pack2(v1.x, v1.y);
      w.w = pack2(v1.z, v1.w);
    }
    *(uint4*)(xb + ((size_t)p * C_ + c8 * 8)) = w;
  }
}

// ---------------------------------------------------------------------------
// f32 fallback path: verbatim R5 kernel (used only if ws_size is too small).
// ---------------------------------------------------------------------------

__device__ __forceinline__ void issue_tap(
    const float* __restrict__ x, float2 oA, float2 oB,
    int i, int di, int jA, int jB, int dj, int b, int c0,
    float& wA00, float& wA01, float& wA10, float& wA11,
    float& wB00, float& wB01, float& wB10, float& wB11,
    f32x4& cA00, f32x4& cA01, f32x4& cA10, f32x4& cA11,
    f32x4& cB00, f32x4& cB01, f32x4& cB10, f32x4& cB11) {
  float yfA = (float)(i + di) + oA.y;
  float xfA = (float)(jA + dj) + oA.x;
  yfA = fminf(fmaxf(yfA, 0.f), HP1F);
  xfA = fminf(fmaxf(xfA, 0.f), HP1F);
  const float y0fA = floorf(yfA), x0fA = floorf(xfA);
  const int y0A = (int)y0fA, x0A = (int)x0fA;

  float yfB = (float)(i + di) + oB.y;
  float xfB = (float)(jB + dj) + oB.x;
  yfB = fminf(fmaxf(yfB, 0.f), HP1F);
  xfB = fminf(fmaxf(xfB, 0.f), HP1F);
  const float y0fB = floorf(yfB), x0fB = floorf(xfB);
  const int y0B = (int)y0fB, x0B = (int)x0fB;

  const int fastA = ((unsigned)(y0A - 1) < 383u) & ((unsigned)(x0A - 1) < 383u);
  const int fastB = ((unsigned)(y0B - 1) < 383u) & ((unsigned)(x0B - 1) < 383u);

  if (__all(fastA & fastB)) {
    const float wy1A = yfA - y0fA, wy0A = (y0fA + 1.0f) - yfA;
    const float wx1A = xfA - x0fA, wx0A = (x0fA + 1.0f) - xfA;
    wA00 = wy0A * wx0A; wA01 = wy0A * wx1A;
    wA10 = wy1A * wx0A; wA11 = wy1A * wx1A;
    const float wy1B = yfB - y0fB, wy0B = (y0fB + 1.0f) - yfB;
    const float wx1B = xfB - x0fB, wx0B = (x0fB + 1.0f) - xfB;
    wB00 = wy0B * wx0B; wB01 = wy0B * wx1B;
    wB10 = wy1B * wx0B; wB11 = wy1B * wx1B;

    const int baseA = ((b * H_ + (y0A - 1)) * W_ + (x0A - 1)) * C_ + c0;
    const int baseB = ((b * H_ + (y0B - 1)) * W_ + (x0B - 1)) * C_ + c0;
    cA00 = *(const f32x4*)(x + baseA);
    cA01 = *(const f32x4*)(x + baseA + C_);
    cA10 = *(const f32x4*)(x + baseA + W_ * C_);
    cA11 = *(const f32x4*)(x + baseA + W_ * C_ + C_);
    cB00 = *(const f32x4*)(x + baseB);
    cB01 = *(const f32x4*)(x + baseB + C_);
    cB10 = *(const f32x4*)(x + baseB + W_ * C_);
    cB11 = *(const f32x4*)(x + baseB + W_ * C_ + C_);
  } else {
    const f32x4 z = {0.f, 0.f, 0.f, 0.f};
    {
      const int y1 = min(y0A + 1, 385);
      const int x1 = min(x0A + 1, 385);
      const float wy1 = yfA - y0fA, wy0 = (float)y1 - yfA;
      const float wx1 = xfA - x0fA, wx0 = (float)x1 - xfA;
      wA00 = wy0 * wx0; wA01 = wy0 * wx1;
      wA10 = wy1 * wx0; wA11 = wy1 * wx1;
      const int yu0 = y0A - 1, xu0 = x0A - 1;
      const bool vy0 = (unsigned)yu0 < 384u, vy1 = (unsigned)(y1 - 1) < 384u;
      const bool vx0 = (unsigned)xu0 < 384u, vx1 = (unsigned)(x1 - 1) < 384u;
      const int base00 = ((b * H_ + yu0) * W_ + xu0) * C_ + c0;
      const int ddx = (x1 - x0A) * C_;
      const int ddy = (y1 - y0A) * (W_ * C_);
      cA00 = z; cA01 = z; cA10 = z; cA11 = z;
      if (vy0 && vx0) cA00 = *(const f32x4*)(x + base00);
      if (vy0 && vx1) cA01 = *(const f32x4*)(x + base00 + ddx);
      if (vy1 && vx0) cA10 = *(const f32x4*)(x + base00 + ddy);
      if (vy1 && vx1) cA11 = *(const f32x4*)(x + base00 + ddy + ddx);
    }
    {
      const int y1 = min(y0B + 1, 385);
      const int x1 = min(x0B + 1, 385);
      const float wy1 = yfB - y0fB, wy0 = (float)y1 - yfB;
      const float wx1 = xfB - x0fB, wx0 = (float)x1 - xfB;
      wB00 = wy0 * wx0; wB01 = wy0 * wx1;
      wB10 = wy1 * wx0; wB11 = wy1 * wx1;
      const int yu0 = y0B - 1, xu0 = x0B - 1;
      const bool vy0 = (unsigned)yu0 < 384u, vy1 = (unsigned)(y1 - 1) < 384u;
      const bool vx0 = (unsigned)xu0 < 384u, vx1 = (unsigned)(x1 - 1) < 384u;
      const int base00 = ((b * H_ + yu0) * W_ + xu0) * C_ + c0;
      const int ddx = (x1 - x0B) * C_;
      const int ddy = (y1 - y0B) * (W_ * C_);
      cB00 = z; cB01 = z; cB10 = z; cB11 = z;
      if (vy0 && vx0) cB00 = *(const f32x4*)(x + base00);
      if (vy0 && vx1) cB01 = *(const f32x4*)(x + base00 + ddx);
      if (vy1 && vx0) cB10 = *(const f32x4*)(x + base00 + ddy);
      if (vy1 && vx1) cB11 = *(const f32x4*)(x + base00 + ddy + ddx);
    }
  }
}

__global__ __launch_bounds__(256) void deform_conv_kernel(
    const float* __restrict__ x, const float* __restrict__ off,
    const float* __restrict__ kern, const float* __restrict__ bias,
    float* __restrict__ out) {
  __shared__ short ldsB[9216];

  const int tid = threadIdx.x;
  const int lane = tid & 63;

  {
    unsigned short* pk = (unsigned short*)ldsB;
    for (int e = tid; e < 1152; e += 256) {
      const int ln = e & 63;
      const int kk = (e >> 6) % 9;
      const int nt = e / 576;
      const int f = nt * 16 + (ln & 15);
      const int q2 = ln >> 4;
      unsigned short rr[8];
#pragma unroll
      for (int i2 = 0; i2 < 8; ++i2) {
        const int c = q2 * 8 + i2;
        rr[i2] = f2bf(kern[(kk * 32 + c) * 32 + f]);
      }
      uint4 w;
      w.x = rr[0] | ((unsigned)rr[1] << 16);
      w.y = rr[2] | ((unsigned)rr[3] << 16);
      w.z = rr[4] | ((unsigned)rr[5] << 16);
      w.w = rr[6] | ((unsigned)rr[7] << 16);
      *(uint4*)&pk[e * 8] = w;
    }
    __syncthreads();
  }
  const short8* bp = (const short8*)ldsB;

  const float bias0 = bias[lane & 15];
  const float bias1 = bias[16 + (lane & 15)];

  const int q  = lane >> 3;
  const int cq = lane & 7;
  const int c0 = cq * 4;

  const int mrow = lane & 15;
  const int qq = lane >> 4;
  const int sl0 = (((mrow & 7) << 3) + (qq << 1)) << 2;
  const int sl1 = sl0 + 4;
  const bool hi = (mrow & 8) != 0;

  const int lb = (blockIdx.x & 7) * 288 + (blockIdx.x >> 3);

  for (int nb = 0; nb < NB; ++nb) {
    const int g = lb * (4 * NB) + nb * 4 + (tid >> 6);
    const int P0 = g << 4;
    const int b = (P0 >= HW_) ? 1 : 0;
    const int rem = P0 - b * HW_;
    const int i = rem / W_;
    const int j0 = rem - i * W_;
    const int jA = j0 + q;
    const int jB = j0 + 8 + q;

    const float* opixA = off + (size_t)(i * W_ + jA) * 18;
    const float* opixB = off + (size_t)(i * W_ + jB) * 18;

    f32x4 acc0 = {bias0, bias0, bias0, bias0};
    f32x4 acc1 = {bias1, bias1, bias1, bias1};

    float wA00, wA01, wA10, wA11, wB00, wB01, wB10, wB11;
    f32x4 cA00, cA01, cA10, cA11, cB00, cB01, cB10, cB11;
    float nA00, nA01, nA10, nA11, nB00, nB01, nB10, nB11;
    f32x4 dA00, dA01, dA10, dA11, dB00, dB01, dB10, dB11;

    float2 oA = *(const float2*)(opixA);
    float2 oB = *(const float2*)(opixB);
    issue_tap(x, oA, oB, i, 0, jA, jB, 0, b, c0,
              wA00, wA01, wA10, wA11, wB00, wB01, wB10, wB11,
              cA00, cA01, cA10, cA11, cB00, cB01, cB10, cB11);
    float2 oA1 = *(const float2*)(opixA + 2);
    float2 oB1 = *(const float2*)(opixB + 2);

#pragma unroll
    for (int kk = 0; kk < 9; ++kk) {
      const f32x4 vA = wA00 * cA00 + wA01 * cA01 + wA10 * cA10 + wA11 * cA11;
      const f32x4 vB = wB00 * cB00 + wB01 * cB01 + wB10 * cB10 + wB11 * cB11;

      if (kk < 8) {
        const int di1 = (kk + 1) / 3;
        const int dj1 = (kk + 1) - di1 * 3;
        issue_tap(x, oA1, oB1, i, di1, jA, jB, dj1, b, c0,
                  nA00, nA01, nA10, nA11, nB00, nB01, nB10, nB11,
                  dA00, dA01, dA10, dA11, dB00, dB01, dB10, dB11);
      }
      if (kk < 7) {
        oA1 = *(const float2*)(opixA + (kk + 2) * 2);
        oB1 = *(const float2*)(opixB + (kk + 2) * 2);
      }

      const int a0 = (int)pack2(vA[0], vA[1]);
      const int a1 = (int)pack2(vA[2], vA[3]);
      const int b0 = (int)pack2(vB[0], vB[1]);
      const int b1 = (int)pack2(vB[2], vB[3]);

      const int pa0 = __builtin_amdgcn_ds_bpermute(sl0, a0);
      const int pb0 = __builtin_amdgcn_ds_bpermute(sl0, b0);
      const int pa1 = __builtin_amdgcn_ds_bpermute(sl0, a1);
      const int pb1 = __builtin_amdgcn_ds_bpermute(sl0, b1);
      const int pa2 = __builtin_amdgcn_ds_bpermute(sl1, a0);
      const int pb2 = __builtin_amdgcn_ds_bpermute(sl1, b0);
      const int pa3 = __builtin_amdgcn_ds_bpermute(sl1, a1);
      const int pb3 = __builtin_amdgcn_ds_bpermute(sl1, b1);
      const uint4v uu = {(unsigned)(hi ? pb0 : pa0), (unsigned)(hi ? pb1 : pa1),
                         (unsigned)(hi ? pb2 : pa2), (unsigned)(hi ? pb3 : pa3)};
      const short8 af = __builtin_bit_cast(short8, uu);

      acc0 = __builtin_amdgcn_mfma_f32_16x16x32_bf16(af, bp[kk * 64 + lane], acc0, 0, 0, 0);
      acc1 = __builtin_amdgcn_mfma_f32_16x16x32_bf16(af, bp[(9 + kk) * 64 + lane], acc1, 0, 0, 0);

      if (kk < 8) {
        wA00 = nA00; wA01 = nA01; wA10 = nA10; wA11 = nA11;
        wB00 = nB00; wB01 = nB01; wB10 = nB10; wB11 = nB11;
        cA00 = dA00; cA01 = dA01; cA10 = dA10; cA11 = dA11;
        cB00 = dB00; cB01 = dB01; cB10 = dB10; cB11 = dB11;
      }
    }

    float* op = out + (size_t)(P0 + qq * 4) * 32 + (lane & 15);
#pragma unroll
    for (int r = 0; r < 4; ++r) {
      op[r * 32] = acc0[r];
      op[r * 32 + 16] = acc1[r];
    }
  }
}

extern "C" void kernel_launch(void* const* d_in, const int* in_sizes, int n_in,
                              void* d_out, int out_size, void* d_ws, size_t ws_size,
                              hipStream_t stream) {
  const float* x    = (const float*)d_in[0];
  const float* off  = (const float*)d_in[1];
  const float* kern = (const float*)d_in[2];
  const float* bias = (const float*)d_in[3];
  float* out = (float*)d_out;

  if (d_ws != nullptr && ws_size >= XPAD_BYTES) {
    unsigned short* xb = (unsigned short*)d_ws;
    cvt_pad_kernel<<<dim3(2048), dim3(256), 0, stream>>>(x, xb);
    deform_conv_d<<<dim3(2304), dim3(256), 0, stream>>>(xb, off, kern, bias, out);
  } else {
    // fallback: proven R5 f32 kernel (no workspace dependency)
    deform_conv_kernel<<<dim3(2304), dim3(256), 0, stream>>>(x, off, kern, bias, out);
  }
}

// Round 17
// 153.060 us; speedup vs baseline: 1.0374x; 1.0374x over previous
//
#include <hip/hip_runtime.h>

typedef short short8 __attribute__((ext_vector_type(8)));
typedef float f32x4 __attribute__((ext_vector_type(4)));
typedef unsigned int uint4v __attribute__((ext_vector_type(4)));

#define H_ 384
#define W_ 384
#define C_ 32
#define HW_ 147456          // H_*W_
#define HP1F 385.0f         // (H+2*pad)-1 as float
#define NB 2                // pixel batches per wave
#define PW 386              // padded width/height
#define PROW (PW * C_)      // 12352 elems per padded row
#define XPAD_ELEMS (2 * PW * PW * C_)   // 9,533,504 bf16
#define XPAD_BYTES ((size_t)XPAD_ELEMS * 2)

__device__ __forceinline__ unsigned short f2bf(float f) {
  unsigned int u = __float_as_uint(f);
  u += 0x7fffu + ((u >> 16) & 1u);   // RNE
  return (unsigned short)(u >> 16);
}

__device__ __forceinline__ unsigned pack2(float a, float b) {
  return (unsigned)f2bf(a) | ((unsigned)f2bf(b) << 16);
}

// 8 bf16 (uint4) -> 8 f32, pure bit ops (exact). Memory order ch0..ch7.
__device__ __forceinline__ void b8_to_f(uint4 r, f32x4& lo, f32x4& hi) {
  lo[0] = __uint_as_float(r.x << 16);
  lo[1] = __uint_as_float(r.x & 0xffff0000u);
  lo[2] = __uint_as_float(r.y << 16);
  lo[3] = __uint_as_float(r.y & 0xffff0000u);
  hi[0] = __uint_as_float(r.z << 16);
  hi[1] = __uint_as_float(r.z & 0xffff0000u);
  hi[2] = __uint_as_float(r.w << 16);
  hi[3] = __uint_as_float(r.w & 0xffff0000u);
}

// ---------------------------------------------------------------------------
// FINAL = R10/R15 (best verified: main ~68us, harness ~154us; R0 was 185.5).
// Structure: padded bf16 image in workspace (branchless unified tap) +
// direct MFMA lane mapping (lane = (pixel mrow, K-slice qq); its 16B corner
// load IS its A fragment -> no crossbar, no LDS slab, 4 gathers/tap).
// Closed levers (counter-evidenced): R5 tap-pipeline neutral; R11 HW-pack
// hurt (VALU=latency filler); R12 occupancy-cap spilled (needs ~80 VGPR);
// R16 dual-stream MLP hurt (compiler serializes streams at 60 VGPR).
// ---------------------------------------------------------------------------

__device__ __forceinline__ void issue_tap_d(
    const unsigned short* __restrict__ xb, float2 o,
    int i, int di, int j, int dj, int b, int c0,
    float& w00, float& w01, float& w10, float& w11,
    uint4& r00, uint4& r01, uint4& r10, uint4& r11) {
  float yf = (float)(i + di) + o.y;   // padded coords; .y = y_off
  float xf = (float)(j + dj) + o.x;   // .x = x_off
  yf = fminf(fmaxf(yf, 0.f), HP1F);
  xf = fminf(fmaxf(xf, 0.f), HP1F);
  const float y0f = floorf(yf), x0f = floorf(xf);
  const int y0 = (int)y0f, x0 = (int)x0f;
  const int y1 = min(y0 + 1, 385), x1 = min(x0 + 1, 385);
  const float wy1 = yf - y0f, wy0 = (float)y1 - yf;
  const float wx1 = xf - x0f, wx0 = (float)x1 - xf;
  w00 = wy0 * wx0; w01 = wy0 * wx1;
  w10 = wy1 * wx0; w11 = wy1 * wx1;
  const int base = ((b * PW + y0) * PW + x0) * C_ + c0;   // 16B-aligned
  const int dx = (x1 - x0) * C_;
  const int dy = (y1 - y0) * PROW;
  // 4 unconditional independent 16B gathers (one per corner, full K-slice)
  r00 = *(const uint4*)(xb + base);
  r01 = *(const uint4*)(xb + base + dx);
  r10 = *(const uint4*)(xb + base + dy);
  r11 = *(const uint4*)(xb + base + dy + dx);
}

__global__ __launch_bounds__(256) void deform_conv_d(
    const unsigned short* __restrict__ xb, const float* __restrict__ off,
    const float* __restrict__ kern, const float* __restrict__ bias,
    float* __restrict__ out) {
  __shared__ short ldsB[9216];

  const int tid = threadIdx.x;
  const int lane = tid & 63;

  // ---- stage packed B fragments (bf16, MFMA B-operand layout) into LDS ----
  {
    unsigned short* pk = (unsigned short*)ldsB;
    for (int e = tid; e < 1152; e += 256) {   // 2 f-tiles * 9 k-steps * 64 lanes
      const int ln = e & 63;
      const int kk = (e >> 6) % 9;
      const int nt = e / 576;
      const int f = nt * 16 + (ln & 15);
      const int q2 = ln >> 4;
      unsigned short rr[8];
#pragma unroll
      for (int i2 = 0; i2 < 8; ++i2) {
        const int c = q2 * 8 + i2;                     // contraction idx = kk*32 + c
        rr[i2] = f2bf(kern[(kk * 32 + c) * 32 + f]);
      }
      uint4 w;
      w.x = rr[0] | ((unsigned)rr[1] << 16);
      w.y = rr[2] | ((unsigned)rr[3] << 16);
      w.z = rr[4] | ((unsigned)rr[5] << 16);
      w.w = rr[6] | ((unsigned)rr[7] << 16);
      *(uint4*)&pk[e * 8] = w;
    }
    __syncthreads();   // only barrier in the kernel
  }
  const short8* bp = (const short8*)ldsB;

  const float bias0 = bias[lane & 15];
  const float bias1 = bias[16 + (lane & 15)];

  // direct MFMA lane mapping: pixel = mrow, K-slice = qq*8..+7
  const int mrow = lane & 15;
  const int qq = lane >> 4;
  const int c0 = qq * 8;

  const int lb = (blockIdx.x & 7) * 288 + (blockIdx.x >> 3);

  for (int nb = 0; nb < NB; ++nb) {
    const int g = lb * (4 * NB) + nb * 4 + (tid >> 6);
    const int P0 = g << 4;
    const int b = (P0 >= HW_) ? 1 : 0;
    const int rem = P0 - b * HW_;
    const int i = rem / W_;
    const int j0 = rem - i * W_;
    const int j = j0 + mrow;          // this lane's pixel column

    // offsets for this lane's pixel (4-way duplicated across qq — merged by L1)
    const float* opix = off + (size_t)(i * W_ + j) * 18;

    f32x4 acc0 = {bias0, bias0, bias0, bias0};
    f32x4 acc1 = {bias1, bias1, bias1, bias1};

    // pipeline state: named regs only (no arrays -> no scratch)
    float wc00, wc01, wc10, wc11;
    uint4 rc00, rc01, rc10, rc11;
    float wn00, wn01, wn10, wn11;
    uint4 rn00, rn01, rn10, rn11;

    float2 oc = *(const float2*)(opix);
    issue_tap_d(xb, oc, i, 0, j, 0, b, c0,
                wc00, wc01, wc10, wc11, rc00, rc01, rc10, rc11);
    float2 o1 = *(const float2*)(opix + 2);

#pragma unroll
    for (int kk = 0; kk < 9; ++kk) {
      // 1. unpack (bit ops) + interp current tap (vmcnt waits land here)
      f32x4 l00, h00, l01, h01, l10, h10, l11, h11;
      b8_to_f(rc00, l00, h00);
      b8_to_f(rc01, l01, h01);
      b8_to_f(rc10, l10, h10);
      b8_to_f(rc11, l11, h11);
      const f32x4 vlo = wc00 * l00 + wc01 * l01 + wc10 * l10 + wc11 * l11;
      const f32x4 vhi = wc00 * h00 + wc01 * h01 + wc10 * h10 + wc11 * h11;

      // 2. issue next tap's gathers (latency hides under step 3)
      if (kk < 8) {
        const int di1 = (kk + 1) / 3;
        const int dj1 = (kk + 1) - di1 * 3;
        issue_tap_d(xb, o1, i, di1, j, dj1, b, c0,
                    wn00, wn01, wn10, wn11, rn00, rn01, rn10, rn11);
      }
      if (kk < 7) o1 = *(const float2*)(opix + (kk + 2) * 2);

      // 3. pack -> MFMA directly (no crossbar: this IS the lane's A fragment)
      const uint4v uu = {pack2(vlo[0], vlo[1]), pack2(vlo[2], vlo[3]),
                         pack2(vhi[0], vhi[1]), pack2(vhi[2], vhi[3])};
      const short8 af = __builtin_bit_cast(short8, uu);

      acc0 = __builtin_amdgcn_mfma_f32_16x16x32_bf16(af, bp[kk * 64 + lane], acc0, 0, 0, 0);
      acc1 = __builtin_amdgcn_mfma_f32_16x16x32_bf16(af, bp[(9 + kk) * 64 + lane], acc1, 0, 0, 0);

      // 4. rotate pipeline state
      if (kk < 8) {
        wc00 = wn00; wc01 = wn01; wc10 = wn10; wc11 = wn11;
        rc00 = rn00; rc01 = rn01; rc10 = rn10; rc11 = rn11;
      }
    }

    // D layout: col = lane&15, row = qq*4 + reg
    float* op = out + (size_t)(P0 + qq * 4) * 32 + (lane & 15);
#pragma unroll
    for (int r = 0; r < 4; ++r) {
      op[r * 32] = acc0[r];
      op[r * 32 + 16] = acc1[r];
    }
  }
}

// pre-pass: x f32 -> PADDED bf16 workspace [2][386][386][32], zero borders.
__global__ __launch_bounds__(256) void cvt_pad_kernel(
    const float* __restrict__ x, unsigned short* __restrict__ xb) {
  const int total = 2 * PW * PW * 4;   // 8-channel groups
  for (int t = blockIdx.x * 256 + threadIdx.x; t < total; t += gridDim.x * 256) {
    const int c8 = t & 3;
    const int p  = t >> 2;             // padded pixel index
    const int xp = p % PW;
    const int yp = (p / PW) % PW;
    const int b  = p / (PW * PW);
    uint4 w = {0u, 0u, 0u, 0u};
    const unsigned py = (unsigned)(yp - 1), px = (unsigned)(xp - 1);
    if (py < 384u && px < 384u) {
      const float* src = x + (((size_t)(b * H_ + (int)py) * W_ + (int)px) * C_ + c8 * 8);
      const float4 v0 = *(const float4*)(src);
      const float4 v1 = *(const float4*)(src + 4);
      w.x = pack2(v0.x, v0.y);
      w.y = pack2(v0.z, v0.w);
      w.z = pack2(v1.x, v1.y);
      w.w = pack2(v1.z, v1.w);
    }
    *(uint4*)(xb + ((size_t)p * C_ + c8 * 8)) = w;
  }
}

// ---------------------------------------------------------------------------
// f32 fallback path: verbatim R5 kernel (used only if ws_size is too small).
// ---------------------------------------------------------------------------

__device__ __forceinline__ void issue_tap(
    const float* __restrict__ x, float2 oA, float2 oB,
    int i, int di, int jA, int jB, int dj, int b, int c0,
    float& wA00, float& wA01, float& wA10, float& wA11,
    float& wB00, float& wB01, float& wB10, float& wB11,
    f32x4& cA00, f32x4& cA01, f32x4& cA10, f32x4& cA11,
    f32x4& cB00, f32x4& cB01, f32x4& cB10, f32x4& cB11) {
  float yfA = (float)(i + di) + oA.y;
  float xfA = (float)(jA + dj) + oA.x;
  yfA = fminf(fmaxf(yfA, 0.f), HP1F);
  xfA = fminf(fmaxf(xfA, 0.f), HP1F);
  const float y0fA = floorf(yfA), x0fA = floorf(xfA);
  const int y0A = (int)y0fA, x0A = (int)x0fA;

  float yfB = (float)(i + di) + oB.y;
  float xfB = (float)(jB + dj) + oB.x;
  yfB = fminf(fmaxf(yfB, 0.f), HP1F);
  xfB = fminf(fmaxf(xfB, 0.f), HP1F);
  const float y0fB = floorf(yfB), x0fB = floorf(xfB);
  const int y0B = (int)y0fB, x0B = (int)x0fB;

  const int fastA = ((unsigned)(y0A - 1) < 383u) & ((unsigned)(x0A - 1) < 383u);
  const int fastB = ((unsigned)(y0B - 1) < 383u) & ((unsigned)(x0B - 1) < 383u);

  if (__all(fastA & fastB)) {
    const float wy1A = yfA - y0fA, wy0A = (y0fA + 1.0f) - yfA;
    const float wx1A = xfA - x0fA, wx0A = (x0fA + 1.0f) - xfA;
    wA00 = wy0A * wx0A; wA01 = wy0A * wx1A;
    wA10 = wy1A * wx0A; wA11 = wy1A * wx1A;
    const float wy1B = yfB - y0fB, wy0B = (y0fB + 1.0f) - yfB;
    const float wx1B = xfB - x0fB, wx0B = (x0fB + 1.0f) - xfB;
    wB00 = wy0B * wx0B; wB01 = wy0B * wx1B;
    wB10 = wy1B * wx0B; wB11 = wy1B * wx1B;

    const int baseA = ((b * H_ + (y0A - 1)) * W_ + (x0A - 1)) * C_ + c0;
    const int baseB = ((b * H_ + (y0B - 1)) * W_ + (x0B - 1)) * C_ + c0;
    cA00 = *(const f32x4*)(x + baseA);
    cA01 = *(const f32x4*)(x + baseA + C_);
    cA10 = *(const f32x4*)(x + baseA + W_ * C_);
    cA11 = *(const f32x4*)(x + baseA + W_ * C_ + C_);
    cB00 = *(const f32x4*)(x + baseB);
    cB01 = *(const f32x4*)(x + baseB + C_);
    cB10 = *(const f32x4*)(x + baseB + W_ * C_);
    cB11 = *(const f32x4*)(x + baseB + W_ * C_ + C_);
  } else {
    const f32x4 z = {0.f, 0.f, 0.f, 0.f};
    {
      const int y1 = min(y0A + 1, 385);
      const int x1 = min(x0A + 1, 385);
      const float wy1 = yfA - y0fA, wy0 = (float)y1 - yfA;
      const float wx1 = xfA - x0fA, wx0 = (float)x1 - xfA;
      wA00 = wy0 * wx0; wA01 = wy0 * wx1;
      wA10 = wy1 * wx0; wA11 = wy1 * wx1;
      const int yu0 = y0A - 1, xu0 = x0A - 1;
      const bool vy0 = (unsigned)yu0 < 384u, vy1 = (unsigned)(y1 - 1) < 384u;
      const bool vx0 = (unsigned)xu0 < 384u, vx1 = (unsigned)(x1 - 1) < 384u;
      const int base00 = ((b * H_ + yu0) * W_ + xu0) * C_ + c0;
      const int ddx = (x1 - x0A) * C_;
      const int ddy = (y1 - y0A) * (W_ * C_);
      cA00 = z; cA01 = z; cA10 = z; cA11 = z;
      if (vy0 && vx0) cA00 = *(const f32x4*)(x + base00);
      if (vy0 && vx1) cA01 = *(const f32x4*)(x + base00 + ddx);
      if (vy1 && vx0) cA10 = *(const f32x4*)(x + base00 + ddy);
      if (vy1 && vx1) cA11 = *(const f32x4*)(x + base00 + ddy + ddx);
    }
    {
      const int y1 = min(y0B + 1, 385);
      const int x1 = min(x0B + 1, 385);
      const float wy1 = yfB - y0fB, wy0 = (float)y1 - yfB;
      const float wx1 = xfB - x0fB, wx0 = (float)x1 - xfB;
      wB00 = wy0 * wx0; wB01 = wy0 * wx1;
      wB10 = wy1 * wx0; wB11 = wy1 * wx1;
      const int yu0 = y0B - 1, xu0 = x0B - 1;
      const bool vy0 = (unsigned)yu0 < 384u, vy1 = (unsigned)(y1 - 1) < 384u;
      const bool vx0 = (unsigned)xu0 < 384u, vx1 = (unsigned)(x1 - 1) < 384u;
      const int base00 = ((b * H_ + yu0) * W_ + xu0) * C_ + c0;
      const int ddx = (x1 - x0B) * C_;
      const int ddy = (y1 - y0B) * (W_ * C_);
      cB00 = z; cB01 = z; cB10 = z; cB11 = z;
      if (vy0 && vx0) cB00 = *(const f32x4*)(x + base00);
      if (vy0 && vx1) cB01 = *(const f32x4*)(x + base00 + ddx);
      if (vy1 && vx0) cB10 = *(const f32x4*)(x + base00 + ddy);
      if (vy1 && vx1) cB11 = *(const f32x4*)(x + base00 + ddy + ddx);
    }
  }
}

__global__ __launch_bounds__(256) void deform_conv_kernel(
    const float* __restrict__ x, const float* __restrict__ off,
    const float* __restrict__ kern, const float* __restrict__ bias,
    float* __restrict__ out) {
  __shared__ short ldsB[9216];

  const int tid = threadIdx.x;
  const int lane = tid & 63;

  {
    unsigned short* pk = (unsigned short*)ldsB;
    for (int e = tid; e < 1152; e += 256) {
      const int ln = e & 63;
      const int kk = (e >> 6) % 9;
      const int nt = e / 576;
      const int f = nt * 16 + (ln & 15);
      const int q2 = ln >> 4;
      unsigned short rr[8];
#pragma unroll
      for (int i2 = 0; i2 < 8; ++i2) {
        const int c = q2 * 8 + i2;
        rr[i2] = f2bf(kern[(kk * 32 + c) * 32 + f]);
      }
      uint4 w;
      w.x = rr[0] | ((unsigned)rr[1] << 16);
      w.y = rr[2] | ((unsigned)rr[3] << 16);
      w.z = rr[4] | ((unsigned)rr[5] << 16);
      w.w = rr[6] | ((unsigned)rr[7] << 16);
      *(uint4*)&pk[e * 8] = w;
    }
    __syncthreads();
  }
  const short8* bp = (const short8*)ldsB;

  const float bias0 = bias[lane & 15];
  const float bias1 = bias[16 + (lane & 15)];

  const int q  = lane >> 3;
  const int cq = lane & 7;
  const int c0 = cq * 4;

  const int mrow = lane & 15;
  const int qq = lane >> 4;
  const int sl0 = (((mrow & 7) << 3) + (qq << 1)) << 2;
  const int sl1 = sl0 + 4;
  const bool hi = (mrow & 8) != 0;

  const int lb = (blockIdx.x & 7) * 288 + (blockIdx.x >> 3);

  for (int nb = 0; nb < NB; ++nb) {
    const int g = lb * (4 * NB) + nb * 4 + (tid >> 6);
    const int P0 = g << 4;
    const int b = (P0 >= HW_) ? 1 : 0;
    const int rem = P0 - b * HW_;
    const int i = rem / W_;
    const int j0 = rem - i * W_;
    const int jA = j0 + q;
    const int jB = j0 + 8 + q;

    const float* opixA = off + (size_t)(i * W_ + jA) * 18;
    const float* opixB = off + (size_t)(i * W_ + jB) * 18;

    f32x4 acc0 = {bias0, bias0, bias0, bias0};
    f32x4 acc1 = {bias1, bias1, bias1, bias1};

    float wA00, wA01, wA10, wA11, wB00, wB01, wB10, wB11;
    f32x4 cA00, cA01, cA10, cA11, cB00, cB01, cB10, cB11;
    float nA00, nA01, nA10, nA11, nB00, nB01, nB10, nB11;
    f32x4 dA00, dA01, dA10, dA11, dB00, dB01, dB10, dB11;

    float2 oA = *(const float2*)(opixA);
    float2 oB = *(const float2*)(opixB);
    issue_tap(x, oA, oB, i, 0, jA, jB, 0, b, c0,
              wA00, wA01, wA10, wA11, wB00, wB01, wB10, wB11,
              cA00, cA01, cA10, cA11, cB00, cB01, cB10, cB11);
    float2 oA1 = *(const float2*)(opixA + 2);
    float2 oB1 = *(const float2*)(opixB + 2);

#pragma unroll
    for (int kk = 0; kk < 9; ++kk) {
      const f32x4 vA = wA00 * cA00 + wA01 * cA01 + wA10 * cA10 + wA11 * cA11;
      const f32x4 vB = wB00 * cB00 + wB01 * cB01 + wB10 * cB10 + wB11 * cB11;

      if (kk < 8) {
        const int di1 = (kk + 1) / 3;
        const int dj1 = (kk + 1) - di1 * 3;
        issue_tap(x, oA1, oB1, i, di1, jA, jB, dj1, b, c0,
                  nA00, nA01, nA10, nA11, nB00, nB01, nB10, nB11,
                  dA00, dA01, dA10, dA11, dB00, dB01, dB10, dB11);
      }
      if (kk < 7) {
        oA1 = *(const float2*)(opixA + (kk + 2) * 2);
        oB1 = *(const float2*)(opixB + (kk + 2) * 2);
      }

      const int a0 = (int)pack2(vA[0], vA[1]);
      const int a1 = (int)pack2(vA[2], vA[3]);
      const int b0 = (int)pack2(vB[0], vB[1]);
      const int b1 = (int)pack2(vB[2], vB[3]);

      const int pa0 = __builtin_amdgcn_ds_bpermute(sl0, a0);
      const int pb0 = __builtin_amdgcn_ds_bpermute(sl0, b0);
      const int pa1 = __builtin_amdgcn_ds_bpermute(sl0, a1);
      const int pb1 = __builtin_amdgcn_ds_bpermute(sl0, b1);
      const int pa2 = __builtin_amdgcn_ds_bpermute(sl1, a0);
      const int pb2 = __builtin_amdgcn_ds_bpermute(sl1, b0);
      const int pa3 = __builtin_amdgcn_ds_bpermute(sl1, a1);
      const int pb3 = __builtin_amdgcn_ds_bpermute(sl1, b1);
      const uint4v uu = {(unsigned)(hi ? pb0 : pa0), (unsigned)(hi ? pb1 : pa1),
                         (unsigned)(hi ? pb2 : pa2), (unsigned)(hi ? pb3 : pa3)};
      const short8 af = __builtin_bit_cast(short8, uu);

      acc0 = __builtin_amdgcn_mfma_f32_16x16x32_bf16(af, bp[kk * 64 + lane], acc0, 0, 0, 0);
      acc1 = __builtin_amdgcn_mfma_f32_16x16x32_bf16(af, bp[(9 + kk) * 64 + lane], acc1, 0, 0, 0);

      if (kk < 8) {
        wA00 = nA00; wA01 = nA01; wA10 = nA10; wA11 = nA11;
        wB00 = nB00; wB01 = nB01; wB10 = nB10; wB11 = nB11;
        cA00 = dA00; cA01 = dA01; cA10 = dA10; cA11 = dA11;
        cB00 = dB00; cB01 = dB01; cB10 = dB10; cB11 = dB11;
      }
    }

    float* op = out + (size_t)(P0 + qq * 4) * 32 + (lane & 15);
#pragma unroll
    for (int r = 0; r < 4; ++r) {
      op[r * 32] = acc0[r];
      op[r * 32 + 16] = acc1[r];
    }
  }
}

extern "C" void kernel_launch(void* const* d_in, const int* in_sizes, int n_in,
                              void* d_out, int out_size, void* d_ws, size_t ws_size,
                              hipStream_t stream) {
  const float* x    = (const float*)d_in[0];
  const float* off  = (const float*)d_in[1];
  const float* kern = (const float*)d_in[2];
  const float* bias = (const float*)d_in[3];
  float* out = (float*)d_out;

  if (d_ws != nullptr && ws_size >= XPAD_BYTES) {
    unsigned short* xb = (unsigned short*)d_ws;
    cvt_pad_kernel<<<dim3(2048), dim3(256), 0, stream>>>(x, xb);
    deform_conv_d<<<dim3(2304), dim3(256), 0, stream>>>(xb, off, kern, bias, out);
  } else {
    // fallback: proven R5 f32 kernel (no workspace dependency)
    deform_conv_kernel<<<dim3(2304), dim3(256), 0, stream>>>(x, off, kern, bias, out);
  }
}